// Round 1
// baseline (2836.142 us; speedup 1.0000x reference)
//
#include <hip/hip_runtime.h>
#include <hip/hip_bf16.h>

#define B_SZ   2
#define LSEQ   1024
#define DD     8
#define DCTRL  256
#define POLY   40
#define NL     2
#define DSTATE 16
#define DCONV  4
#define DINNER 256
#define DTRANK 16
#define NBL    (B_SZ*LSEQ)        // 2048
#define NROWS  (2*DD*POLY*POLY)   // 25600
#define NSLOT  25                 // 1600/64 r-tiles per channel

__device__ __forceinline__ float sigmoidf_(float x){ return 1.f/(1.f+__expf(-x)); }
__device__ __forceinline__ float softplusf_(float x){ return fmaxf(x,0.f) + log1pf(__expf(-fabsf(x))); }

// ---- pm[b,l,c,j] = z^j, z = concat([x, y-x]) in ORIGINAL l order ----
__global__ void k_pm(const float* __restrict__ x, const float* __restrict__ y,
                     float* __restrict__ pm){
  int idx = blockIdx.x*blockDim.x + threadIdx.x;   // (b*L+l)*16+c
  if (idx >= NBL*16) return;
  int c = idx & 15; int m = idx >> 4;
  float z;
  if (c < 8) z = x[(size_t)m*8 + c];
  else       z = y[(size_t)m*8 + (c-8)] - x[(size_t)m*8 + (c-8)];
  float p = 1.f;
  float* o = pm + (size_t)idx*POLY;
  #pragma unroll
  for (int j=0;j<POLY;++j){ o[j]=p; p*=z; }
}

// ---- ctrl_in (flipped seq) @ control_proj_w.T + b  ->  u (mamba order) ----
__global__ void k_ctrl(const float* __restrict__ x, const float* __restrict__ y,
                       const float* __restrict__ w, const float* __restrict__ b,
                       float* __restrict__ u){
  int idx = blockIdx.x*blockDim.x + threadIdx.x;   // (b*L+lm)*256+e
  if (idx >= NBL*DCTRL) return;
  int e = idx & 255; int m = idx >> 8;
  int bb = m >> 10; int lm = m & 1023; int lo = 1023 - lm;
  const float* xp = x + ((size_t)bb*1024+lo)*8;
  const float* yp = y + ((size_t)bb*1024+lo)*8;
  const float* wr = w + (size_t)e*16;
  float acc = b[e];
  #pragma unroll
  for (int d=0; d<8; ++d) acc += (yp[d]-xp[d])*wr[d];   // xdot part
  #pragma unroll
  for (int d=0; d<8; ++d) acc += yp[d]*wr[8+d];         // y part
  u[idx] = acc;
}

// ---- rmsnorm: one block per (b,l) row ----
__global__ void k_rms(const float* __restrict__ u, const float* __restrict__ nw,
                      float* __restrict__ r){
  int m = blockIdx.x; int e = threadIdx.x;
  float v = u[(size_t)m*256 + e];
  float ss = v*v;
  #pragma unroll
  for (int off=32; off>0; off>>=1) ss += __shfl_down(ss, off);
  __shared__ float sred[4];
  __shared__ float srstd;
  int wid = e>>6; int lane = e&63;
  if (lane==0) sred[wid]=ss;
  __syncthreads();
  if (e==0){ float t = sred[0]+sred[1]+sred[2]+sred[3]; srstd = rsqrtf(t*(1.f/256.f) + 1e-5f); }
  __syncthreads();
  r[(size_t)m*256+e] = v * srstd * nw[e];
}

// ---- generic NT gemm: C[m,n] = dot(A[m,:K],B[n,:K]) (+bias[n]) (+C) ----
__global__ void gemm_nt(const float* __restrict__ A, int lda,
                        const float* __restrict__ B, int ldb,
                        const float* __restrict__ bias,
                        float* __restrict__ C, int ldc,
                        int M, int N, int K, int addC){
  __shared__ float As[64][17];
  __shared__ float Bs[64][17];
  int tid = threadIdx.x;
  int tx = tid & 15, ty = tid >> 4;
  int m0 = blockIdx.y*64, n0 = blockIdx.x*64;
  float acc[4][4] = {};
  for (int k0=0; k0<K; k0+=16){
    #pragma unroll
    for (int q=0;q<4;++q){
      int idx = tid + q*256; int row = idx>>4, col = idx&15;
      int am = m0+row, ak = k0+col;
      As[row][col] = (am<M && ak<K) ? A[(size_t)am*lda+ak] : 0.f;
      int bn = n0+row;
      Bs[row][col] = (bn<N && ak<K) ? B[(size_t)bn*ldb+ak] : 0.f;
    }
    __syncthreads();
    #pragma unroll
    for (int kk=0;kk<16;++kk){
      float a[4], bv[4];
      #pragma unroll
      for (int i=0;i<4;++i) a[i]=As[ty*4+i][kk];
      #pragma unroll
      for (int j=0;j<4;++j) bv[j]=Bs[tx*4+j][kk];
      #pragma unroll
      for (int i=0;i<4;++i)
        #pragma unroll
        for (int j=0;j<4;++j) acc[i][j] += a[i]*bv[j];
    }
    __syncthreads();
  }
  #pragma unroll
  for (int i=0;i<4;++i){
    int m=m0+ty*4+i; if (m>=M) continue;
    #pragma unroll
    for (int j=0;j<4;++j){
      int n=n0+tx*4+j; if (n>=N) continue;
      float v = acc[i][j];
      if (bias) v += bias[n];
      if (addC) v += C[(size_t)m*ldc+n];
      C[(size_t)m*ldc+n]=v;
    }
  }
}

// ---- causal conv (K=4) + bias + silu on xc half of xz ----
__global__ void k_convsilu(const float* __restrict__ xz, const float* __restrict__ cw,
                           const float* __restrict__ cb, float* __restrict__ xc){
  int idx = blockIdx.x*blockDim.x + threadIdx.x;  // m*256+d
  if (idx >= NBL*256) return;
  int d = idx & 255; int m = idx >> 8;
  int bb = m>>10, l = m&1023;
  const float* w = cw + d*4;
  float acc = cb[d];
  #pragma unroll
  for (int k=0;k<4;++k){
    int ls = l - 3 + k;
    if (ls >= 0) acc += xz[((size_t)(bb*1024+ls))*512 + d] * w[k];
  }
  xc[idx] = acc * sigmoidf_(acc);
}

// ---- selective scan: thread = (b, d, s); 16-lane reduce for y ----
__global__ void k_scan(const float* __restrict__ delta_pre, const float* __restrict__ dtb,
                       const float* __restrict__ dbc, const float* __restrict__ xc,
                       const float* __restrict__ xz, const float* __restrict__ alog,
                       const float* __restrict__ dskip, float* __restrict__ yv){
  int blk = blockIdx.x;              // b*16 + dgroup
  int bb = blk >> 4; int dg = blk & 15;
  int tid = threadIdx.x;
  int dl = tid >> 4; int s = tid & 15;
  int d = dg*16 + dl;
  float A  = -__expf(alog[(size_t)d*16+s]);
  float dsk = dskip[d];
  float bt  = dtb[d];
  float h = 0.f;
  size_t base = (size_t)bb*1024;
  #pragma unroll 4
  for (int t=0;t<1024;++t){
    size_t mb = base + t;
    float dp = delta_pre[mb*256+d] + bt;
    float delta = softplusf_(dp);
    float Bv  = dbc[mb*48+16+s];
    float Cv  = dbc[mb*48+32+s];
    float xcv = xc[mb*256+d];
    float dA = __expf(delta*A);
    h = dA*h + delta*Bv*xcv;
    float yval = h*Cv;
    yval += __shfl_xor(yval,1);
    yval += __shfl_xor(yval,2);
    yval += __shfl_xor(yval,4);
    yval += __shfl_xor(yval,8);
    if (s==0){
      float zg = xz[mb*512+256+d];
      yv[mb*256+d] = (yval + dsk*xcv) * zg * sigmoidf_(zg);
    }
  }
}

// ---- flip u back to original order: state_pred out + ws copy for b_net ----
__global__ void k_storesp(const float* __restrict__ u, float* __restrict__ sp,
                          float* __restrict__ outsp){
  int idx = blockIdx.x*blockDim.x+threadIdx.x;   // m_orig*256+e
  if (idx>=NBL*256) return;
  int e = idx & 255; int m = idx >> 8;
  int bb=m>>10, l=m&1023;
  float v = u[((size_t)(bb*1024 + (1023-l)))*256 + e];
  sp[idx]=v; outsp[idx]=v;
}

// ---- fused b_net GEMM + bilinear pm contraction -> partials (no atomics) ----
__global__ void k_bnet(const float* __restrict__ sp, const float* __restrict__ W,
                       const float* __restrict__ bnb, const float* __restrict__ pm,
                       float* __restrict__ part){
  __shared__ float As[64][17];
  __shared__ float Bs[64][17];
  __shared__ float red[64][17];
  int tid=threadIdx.x; int tx=tid&15, ty=tid>>4;
  int n0=blockIdx.x*64, m0=blockIdx.y*64;
  float acc[4][4]={};
  for (int k0=0;k0<256;k0+=16){
    #pragma unroll
    for (int q=0;q<4;++q){
      int idx=tid+q*256; int row=idx>>4,col=idx&15;
      As[row][col]=sp[(size_t)(m0+row)*256+k0+col];
      Bs[row][col]=W [(size_t)(n0+row)*256+k0+col];
    }
    __syncthreads();
    #pragma unroll
    for (int kk=0;kk<16;++kk){
      float a[4], bv[4];
      #pragma unroll
      for (int i=0;i<4;++i) a[i]=As[ty*4+i][kk];
      #pragma unroll
      for (int j=0;j<4;++j) bv[j]=Bs[tx*4+j][kk];
      #pragma unroll
      for (int i=0;i<4;++i)
        #pragma unroll
        for (int j=0;j<4;++j) acc[i][j] += a[i]*bv[j];
    }
    __syncthreads();
  }
  // epilogue: row r = n0+.. = c*1600 + k*40 + j ; all 64 rows share c
  int c    = n0/1600;
  int slot = (n0%1600)/64;
  #pragma unroll
  for (int i=0;i<4;++i){
    int m=m0+ty*4+i;
    float s_=0.f;
    #pragma unroll
    for (int j=0;j<4;++j){
      int n=n0+tx*4+j;
      int rem=n%1600; int k=rem/40; int jj=rem%40;
      float q = pm[((size_t)m*16+c)*40+k] * pm[((size_t)m*16+(15-c))*40+jj];
      s_ += (acc[i][j]+bnb[n])*q;
    }
    red[ty*4+i][tx]=s_;
  }
  __syncthreads();
  if (tid<64){
    float t=0.f;
    #pragma unroll
    for (int q=0;q<16;++q) t+=red[tid][q];
    part[((size_t)slot*NBL + (m0+tid))*16 + c] = t;
  }
}

// ---- final zdot: sum 25 partials, drop l=0 ----
__global__ void k_final(const float* __restrict__ part, float* __restrict__ out){
  int idx=blockIdx.x*blockDim.x+threadIdx.x;   // (b*1023+(l-1))*16+c
  if (idx >= B_SZ*1023*16) return;
  int c = idx & 15; int t = idx >> 4; int bb = t / 1023; int l = t % 1023 + 1;
  size_t m = (size_t)bb*1024 + l;
  float s = 0.f;
  #pragma unroll
  for (int q=0;q<NSLOT;++q) s += part[((size_t)q*NBL + m)*16 + c];
  out[idx] = s;
}

extern "C" void kernel_launch(void* const* d_in, const int* in_sizes, int n_in,
                              void* d_out, int out_size, void* d_ws, size_t ws_size,
                              hipStream_t stream) {
  const float* x    = (const float*)d_in[0];
  const float* y    = (const float*)d_in[1];
  const float* cpw  = (const float*)d_in[2];
  const float* cpb  = (const float*)d_in[3];
  const float* nw   = (const float*)d_in[4];
  const float* ipw  = (const float*)d_in[5];
  const float* cvw  = (const float*)d_in[6];
  const float* cvb  = (const float*)d_in[7];
  const float* xpw  = (const float*)d_in[8];
  const float* dtw  = (const float*)d_in[9];
  const float* dtb  = (const float*)d_in[10];
  const float* alog = (const float*)d_in[11];
  const float* dsk  = (const float*)d_in[12];
  const float* opw  = (const float*)d_in[13];
  const float* bnw  = (const float*)d_in[14];
  const float* bnb  = (const float*)d_in[15];

  float* out      = (float*)d_out;
  float* out_zdot = out;                 // 2*1023*16 = 32736
  float* out_sp   = out + 32736;         // 2*1024*256 = 524288

  float* ws = (float*)d_ws;
  size_t off = 0;
  float* u    = ws + off; off += (size_t)NBL*256;
  float* r    = ws + off; off += (size_t)NBL*256;
  float* xz   = ws + off; off += (size_t)NBL*512;
  float* xc   = ws + off; off += (size_t)NBL*256;
  float* dbc  = ws + off; off += (size_t)NBL*48;
  float* dpre = ws + off; off += (size_t)NBL*256;
  float* yv   = ws + off; off += (size_t)NBL*256;
  float* sp   = ws + off; off += (size_t)NBL*256;
  float* pm   = ws + off; off += (size_t)NBL*16*POLY;
  float* part = ws + off; off += (size_t)NSLOT*NBL*16;

  k_pm  <<<(NBL*16+255)/256, 256, 0, stream>>>(x, y, pm);
  k_ctrl<<<(NBL*256+255)/256, 256, 0, stream>>>(x, y, cpw, cpb, u);

  for (int i=0;i<NL;++i){
    k_rms<<<NBL, 256, 0, stream>>>(u, nw + i*256, r);
    gemm_nt<<<dim3(512/64, NBL/64), 256, 0, stream>>>(r, 256, ipw + (size_t)i*512*256, 256,
                                                      nullptr, xz, 512, NBL, 512, 256, 0);
    k_convsilu<<<(NBL*256+255)/256, 256, 0, stream>>>(xz, cvw + i*256*4, cvb + i*256, xc);
    gemm_nt<<<dim3(1, NBL/64), 256, 0, stream>>>(xc, 256, xpw + (size_t)i*48*256, 256,
                                                 nullptr, dbc, 48, NBL, 48, 256, 0);
    gemm_nt<<<dim3(4, NBL/64), 256, 0, stream>>>(dbc, 48, dtw + (size_t)i*256*16, 16,
                                                 nullptr, dpre, 256, NBL, 256, 16, 0);
    k_scan<<<B_SZ*16, 256, 0, stream>>>(dpre, dtb + i*256, dbc, xc, xz,
                                        alog + (size_t)i*256*16, dsk + i*256, yv);
    gemm_nt<<<dim3(4, NBL/64), 256, 0, stream>>>(yv, 256, opw + (size_t)i*256*256, 256,
                                                 nullptr, u, 256, NBL, 256, 256, 1);
  }

  k_storesp<<<(NBL*256+255)/256, 256, 0, stream>>>(u, sp, out_sp);
  k_bnet<<<dim3(NROWS/64, NBL/64), 256, 0, stream>>>(sp, bnw, bnb, pm, part);
  k_final<<<(B_SZ*1023*16+255)/256, 256, 0, stream>>>(part, out_zdot);
}

// Round 2
// 944.183 us; speedup vs baseline: 3.0038x; 3.0038x over previous
//
#include <hip/hip_runtime.h>
#include <hip/hip_bf16.h>

#define B_SZ   2
#define LSEQ   1024
#define DD     8
#define DCTRL  256
#define POLY   40
#define NL     2
#define DSTATE 16
#define DCONV  4
#define DINNER 256
#define DTRANK 16
#define NBL    (B_SZ*LSEQ)        // 2048
#define NROWS  (2*DD*POLY*POLY)   // 25600
#define NSLOT  25                 // 1600/64 r-tiles per channel
#define NCH    16                 // scan chunks
#define LCH    64                 // chunk length

__device__ __forceinline__ float sigmoidf_(float x){ return 1.f/(1.f+__expf(-x)); }
__device__ __forceinline__ float softplusf_(float x){ return fmaxf(x,0.f) + log1pf(__expf(-fabsf(x))); }

// ---- pm[b,l,c,j] = z^j, z = concat([x, y-x]) in ORIGINAL l order ----
__global__ void k_pm(const float* __restrict__ x, const float* __restrict__ y,
                     float* __restrict__ pm){
  int idx = blockIdx.x*blockDim.x + threadIdx.x;   // (b*L+l)*16+c
  if (idx >= NBL*16) return;
  int c = idx & 15; int m = idx >> 4;
  float z;
  if (c < 8) z = x[(size_t)m*8 + c];
  else       z = y[(size_t)m*8 + (c-8)] - x[(size_t)m*8 + (c-8)];
  float p = 1.f;
  float* o = pm + (size_t)idx*POLY;
  #pragma unroll
  for (int j=0;j<POLY;++j){ o[j]=p; p*=z; }
}

// ---- ctrl_in (flipped seq) @ control_proj_w.T + b  ->  u (mamba order) ----
__global__ void k_ctrl(const float* __restrict__ x, const float* __restrict__ y,
                       const float* __restrict__ w, const float* __restrict__ b,
                       float* __restrict__ u){
  int idx = blockIdx.x*blockDim.x + threadIdx.x;   // (b*L+lm)*256+e
  if (idx >= NBL*DCTRL) return;
  int e = idx & 255; int m = idx >> 8;
  int bb = m >> 10; int lm = m & 1023; int lo = 1023 - lm;
  const float* xp = x + ((size_t)bb*1024+lo)*8;
  const float* yp = y + ((size_t)bb*1024+lo)*8;
  const float* wr = w + (size_t)e*16;
  float acc = b[e];
  #pragma unroll
  for (int d=0; d<8; ++d) acc += (yp[d]-xp[d])*wr[d];   // xdot part
  #pragma unroll
  for (int d=0; d<8; ++d) acc += yp[d]*wr[8+d];         // y part
  u[idx] = acc;
}

// ---- rmsnorm: one block per (b,l) row ----
__global__ void k_rms(const float* __restrict__ u, const float* __restrict__ nw,
                      float* __restrict__ r){
  int m = blockIdx.x; int e = threadIdx.x;
  float v = u[(size_t)m*256 + e];
  float ss = v*v;
  #pragma unroll
  for (int off=32; off>0; off>>=1) ss += __shfl_down(ss, off);
  __shared__ float sred[4];
  __shared__ float srstd;
  int wid = e>>6; int lane = e&63;
  if (lane==0) sred[wid]=ss;
  __syncthreads();
  if (e==0){ float t = sred[0]+sred[1]+sred[2]+sred[3]; srstd = rsqrtf(t*(1.f/256.f) + 1e-5f); }
  __syncthreads();
  r[(size_t)m*256+e] = v * srstd * nw[e];
}

// ---- generic NT gemm: C[m,n] = dot(A[m,:K],B[n,:K]) (+bias[n]) (+C) (act) ----
__global__ void gemm_nt(const float* __restrict__ A, int lda,
                        const float* __restrict__ B, int ldb,
                        const float* __restrict__ bias,
                        float* __restrict__ C, int ldc,
                        int M, int N, int K, int addC, int act){
  __shared__ float As[64][17];
  __shared__ float Bs[64][17];
  int tid = threadIdx.x;
  int tx = tid & 15, ty = tid >> 4;
  int m0 = blockIdx.y*64, n0 = blockIdx.x*64;
  float acc[4][4] = {};
  for (int k0=0; k0<K; k0+=16){
    #pragma unroll
    for (int q=0;q<4;++q){
      int idx = tid + q*256; int row = idx>>4, col = idx&15;
      int am = m0+row, ak = k0+col;
      As[row][col] = (am<M && ak<K) ? A[(size_t)am*lda+ak] : 0.f;
      int bn = n0+row;
      Bs[row][col] = (bn<N && ak<K) ? B[(size_t)bn*ldb+ak] : 0.f;
    }
    __syncthreads();
    #pragma unroll
    for (int kk=0;kk<16;++kk){
      float a[4], bv[4];
      #pragma unroll
      for (int i=0;i<4;++i) a[i]=As[ty*4+i][kk];
      #pragma unroll
      for (int j=0;j<4;++j) bv[j]=Bs[tx*4+j][kk];
      #pragma unroll
      for (int i=0;i<4;++i)
        #pragma unroll
        for (int j=0;j<4;++j) acc[i][j] += a[i]*bv[j];
    }
    __syncthreads();
  }
  #pragma unroll
  for (int i=0;i<4;++i){
    int m=m0+ty*4+i; if (m>=M) continue;
    #pragma unroll
    for (int j=0;j<4;++j){
      int n=n0+tx*4+j; if (n>=N) continue;
      float v = acc[i][j];
      if (bias) v += bias[n];
      if (act==1) v = softplusf_(v);
      if (addC) v += C[(size_t)m*ldc+n];
      C[(size_t)m*ldc+n]=v;
    }
  }
}

// ---- causal conv (K=4) + bias + silu on xc half of xz ----
__global__ void k_convsilu(const float* __restrict__ xz, const float* __restrict__ cw,
                           const float* __restrict__ cb, float* __restrict__ xc){
  int idx = blockIdx.x*blockDim.x + threadIdx.x;  // m*256+d
  if (idx >= NBL*256) return;
  int d = idx & 255; int m = idx >> 8;
  int bb = m>>10, l = m&1023;
  const float* w = cw + d*4;
  float acc = cb[d];
  #pragma unroll
  for (int k=0;k<4;++k){
    int ls = l - 3 + k;
    if (ls >= 0) acc += xz[((size_t)(bb*1024+ls))*512 + d] * w[k];
  }
  xc[idx] = acc * sigmoidf_(acc);
}

// ---- chunked scan pass 1: per-chunk local end-state + cumprod ----
// thread = (b, chunk, d, s); block = 16 d x 16 s
__global__ void k_scan1(const float* __restrict__ delta, const float* __restrict__ dbc,
                        const float* __restrict__ xc, const float* __restrict__ alog,
                        float* __restrict__ hend, float* __restrict__ Pc){
  int blk = blockIdx.x;              // (bb*NCH + ch)*16 + dg
  int dg = blk & 15; int ch = (blk>>4) & 15; int bb = blk>>8;
  int tid = threadIdx.x; int dl = tid>>4; int s = tid&15; int d = dg*16+dl;
  float A = -__expf(alog[(size_t)d*16+s]);
  float h = 0.f, p = 1.f;
  size_t base = (size_t)bb*1024 + ch*LCH;
  #pragma unroll 4
  for (int t=0;t<LCH;++t){
    size_t mb = base + t;
    float de  = delta[mb*256+d];
    float Bv  = dbc[mb*48+16+s];
    float xcv = xc[mb*256+d];
    float a = __expf(de*A);
    h = a*h + de*Bv*xcv;
    p *= a;
  }
  size_t o = (((size_t)bb*NCH+ch)*256+d)*16+s;
  hend[o]=h; Pc[o]=p;
}

// ---- pass 2: chunk-level recurrence, store per-chunk initial state ----
__global__ void k_scan2(const float* __restrict__ hend, const float* __restrict__ Pc,
                        float* __restrict__ Hinit){
  int idx = blockIdx.x*blockDim.x + threadIdx.x;  // bb*4096 + d*16+s
  if (idx >= B_SZ*256*16) return;
  int bb = idx >> 12; int ds = idx & 4095;
  float H = 0.f;
  #pragma unroll
  for (int ch=0; ch<NCH; ++ch){
    size_t o = ((size_t)bb*NCH+ch)*4096 + ds;
    Hinit[o] = H;
    H = Pc[o]*H + hend[o];
  }
}

// ---- pass 3: re-run chunks from correct init, emit gated y ----
__global__ void k_scan3(const float* __restrict__ delta, const float* __restrict__ dbc,
                        const float* __restrict__ xc, const float* __restrict__ xz,
                        const float* __restrict__ alog, const float* __restrict__ dskip,
                        const float* __restrict__ Hinit, float* __restrict__ yv){
  int blk = blockIdx.x;
  int dg = blk & 15; int ch = (blk>>4) & 15; int bb = blk>>8;
  int tid = threadIdx.x; int dl = tid>>4; int s = tid&15; int d = dg*16+dl;
  float A = -__expf(alog[(size_t)d*16+s]);
  float dsk = dskip[d];
  float h = Hinit[(((size_t)bb*NCH+ch)*256+d)*16+s];
  size_t base = (size_t)bb*1024 + ch*LCH;
  #pragma unroll 2
  for (int t=0;t<LCH;++t){
    size_t mb = base + t;
    float de  = delta[mb*256+d];
    float Bv  = dbc[mb*48+16+s];
    float Cv  = dbc[mb*48+32+s];
    float xcv = xc[mb*256+d];
    float a = __expf(de*A);
    h = a*h + de*Bv*xcv;
    float yval = h*Cv;
    yval += __shfl_xor(yval,1);
    yval += __shfl_xor(yval,2);
    yval += __shfl_xor(yval,4);
    yval += __shfl_xor(yval,8);
    if (s==0){
      float zg = xz[mb*512+256+d];
      yv[mb*256+d] = (yval + dsk*xcv) * zg * sigmoidf_(zg);
    }
  }
}

// ---- flip u back to original order: state_pred out + ws copy for b_net ----
__global__ void k_storesp(const float* __restrict__ u, float* __restrict__ sp,
                          float* __restrict__ outsp){
  int idx = blockIdx.x*blockDim.x+threadIdx.x;   // m_orig*256+e
  if (idx>=NBL*256) return;
  int e = idx & 255; int m = idx >> 8;
  int bb=m>>10, l=m&1023;
  float v = u[((size_t)(bb*1024 + (1023-l)))*256 + e];
  sp[idx]=v; outsp[idx]=v;
}

// ---- fused b_net GEMM + bilinear pm contraction -> partials (no atomics) ----
__global__ void k_bnet(const float* __restrict__ sp, const float* __restrict__ W,
                       const float* __restrict__ bnb, const float* __restrict__ pm,
                       float* __restrict__ part){
  __shared__ float As[64][17];
  __shared__ float Bs[64][17];
  __shared__ float red[64][17];
  int tid=threadIdx.x; int tx=tid&15, ty=tid>>4;
  int n0=blockIdx.x*64, m0=blockIdx.y*64;
  float acc[4][4]={};
  for (int k0=0;k0<256;k0+=16){
    #pragma unroll
    for (int q=0;q<4;++q){
      int idx=tid+q*256; int row=idx>>4,col=idx&15;
      As[row][col]=sp[(size_t)(m0+row)*256+k0+col];
      Bs[row][col]=W [(size_t)(n0+row)*256+k0+col];
    }
    __syncthreads();
    #pragma unroll
    for (int kk=0;kk<16;++kk){
      float a[4], bv[4];
      #pragma unroll
      for (int i=0;i<4;++i) a[i]=As[ty*4+i][kk];
      #pragma unroll
      for (int j=0;j<4;++j) bv[j]=Bs[tx*4+j][kk];
      #pragma unroll
      for (int i=0;i<4;++i)
        #pragma unroll
        for (int j=0;j<4;++j) acc[i][j] += a[i]*bv[j];
    }
    __syncthreads();
  }
  int c    = n0/1600;
  int slot = (n0%1600)/64;
  #pragma unroll
  for (int i=0;i<4;++i){
    int m=m0+ty*4+i;
    float s_=0.f;
    #pragma unroll
    for (int j=0;j<4;++j){
      int n=n0+tx*4+j;
      int rem=n%1600; int k=rem/40; int jj=rem%40;
      float q = pm[((size_t)m*16+c)*40+k] * pm[((size_t)m*16+(15-c))*40+jj];
      s_ += (acc[i][j]+bnb[n])*q;
    }
    red[ty*4+i][tx]=s_;
  }
  __syncthreads();
  if (tid<64){
    float t=0.f;
    #pragma unroll
    for (int q=0;q<16;++q) t+=red[tid][q];
    part[((size_t)slot*NBL + (m0+tid))*16 + c] = t;
  }
}

// ---- final zdot: sum 25 partials, drop l=0 ----
__global__ void k_final(const float* __restrict__ part, float* __restrict__ out){
  int idx=blockIdx.x*blockDim.x+threadIdx.x;   // (b*1023+(l-1))*16+c
  if (idx >= B_SZ*1023*16) return;
  int c = idx & 15; int t = idx >> 4; int bb = t / 1023; int l = t % 1023 + 1;
  size_t m = (size_t)bb*1024 + l;
  float s = 0.f;
  #pragma unroll
  for (int q=0;q<NSLOT;++q) s += part[((size_t)q*NBL + m)*16 + c];
  out[idx] = s;
}

extern "C" void kernel_launch(void* const* d_in, const int* in_sizes, int n_in,
                              void* d_out, int out_size, void* d_ws, size_t ws_size,
                              hipStream_t stream) {
  const float* x    = (const float*)d_in[0];
  const float* y    = (const float*)d_in[1];
  const float* cpw  = (const float*)d_in[2];
  const float* cpb  = (const float*)d_in[3];
  const float* nw   = (const float*)d_in[4];
  const float* ipw  = (const float*)d_in[5];
  const float* cvw  = (const float*)d_in[6];
  const float* cvb  = (const float*)d_in[7];
  const float* xpw  = (const float*)d_in[8];
  const float* dtw  = (const float*)d_in[9];
  const float* dtb  = (const float*)d_in[10];
  const float* alog = (const float*)d_in[11];
  const float* dsk  = (const float*)d_in[12];
  const float* opw  = (const float*)d_in[13];
  const float* bnw  = (const float*)d_in[14];
  const float* bnb  = (const float*)d_in[15];

  float* out      = (float*)d_out;
  float* out_zdot = out;                 // 2*1023*16 = 32736
  float* out_sp   = out + 32736;         // 2*1024*256 = 524288

  float* ws = (float*)d_ws;
  size_t off = 0;
  float* u     = ws + off; off += (size_t)NBL*256;
  float* r     = ws + off; off += (size_t)NBL*256;
  float* xz    = ws + off; off += (size_t)NBL*512;
  float* xc    = ws + off; off += (size_t)NBL*256;
  float* dbc   = ws + off; off += (size_t)NBL*48;
  float* delta = ws + off; off += (size_t)NBL*256;
  float* yv    = ws + off; off += (size_t)NBL*256;
  float* sp    = ws + off; off += (size_t)NBL*256;
  float* pm    = ws + off; off += (size_t)NBL*16*POLY;
  float* part  = ws + off; off += (size_t)NSLOT*NBL*16;
  float* hend  = ws + off; off += (size_t)B_SZ*NCH*256*16;
  float* Pc    = ws + off; off += (size_t)B_SZ*NCH*256*16;
  float* Hinit = ws + off; off += (size_t)B_SZ*NCH*256*16;

  k_pm  <<<(NBL*16+255)/256, 256, 0, stream>>>(x, y, pm);
  k_ctrl<<<(NBL*256+255)/256, 256, 0, stream>>>(x, y, cpw, cpb, u);

  for (int i=0;i<NL;++i){
    k_rms<<<NBL, 256, 0, stream>>>(u, nw + i*256, r);
    gemm_nt<<<dim3(512/64, NBL/64), 256, 0, stream>>>(r, 256, ipw + (size_t)i*512*256, 256,
                                                      nullptr, xz, 512, NBL, 512, 256, 0, 0);
    k_convsilu<<<(NBL*256+255)/256, 256, 0, stream>>>(xz, cvw + i*256*4, cvb + i*256, xc);
    gemm_nt<<<dim3(1, NBL/64), 256, 0, stream>>>(xc, 256, xpw + (size_t)i*48*256, 256,
                                                 nullptr, dbc, 48, NBL, 48, 256, 0, 0);
    // delta = softplus(dbc[:, :16] @ dtw^T + dtb)
    gemm_nt<<<dim3(4, NBL/64), 256, 0, stream>>>(dbc, 48, dtw + (size_t)i*256*16, 16,
                                                 dtb + i*256, delta, 256, NBL, 256, 16, 0, 1);
    k_scan1<<<B_SZ*NCH*16, 256, 0, stream>>>(delta, dbc, xc, alog + (size_t)i*256*16, hend, Pc);
    k_scan2<<<(B_SZ*256*16+255)/256, 256, 0, stream>>>(hend, Pc, Hinit);
    k_scan3<<<B_SZ*NCH*16, 256, 0, stream>>>(delta, dbc, xc, xz, alog + (size_t)i*256*16,
                                             dsk + i*256, Hinit, yv);
    gemm_nt<<<dim3(4, NBL/64), 256, 0, stream>>>(yv, 256, opw + (size_t)i*256*256, 256,
                                                 nullptr, u, 256, NBL, 256, 256, 1, 0);
  }

  k_storesp<<<(NBL*256+255)/256, 256, 0, stream>>>(u, sp, out_sp);
  k_bnet<<<dim3(NROWS/64, NBL/64), 256, 0, stream>>>(sp, bnw, bnb, pm, part);
  k_final<<<(B_SZ*1023*16+255)/256, 256, 0, stream>>>(part, out_zdot);
}

// Round 4
// 551.701 us; speedup vs baseline: 5.1407x; 1.7114x over previous
//
#include <hip/hip_runtime.h>
#include <hip/hip_bf16.h>

#define B_SZ   2
#define LSEQ   1024
#define DD     8
#define DCTRL  256
#define POLY   40
#define NL     2
#define DSTATE 16
#define DCONV  4
#define DINNER 256
#define DTRANK 16
#define NBL    (B_SZ*LSEQ)        // 2048
#define NROWS  (2*DD*POLY*POLY)   // 25600
#define NSLOT  25                 // 1600/64 r-tiles per channel
#define NCH    16                 // scan chunks
#define LCH    64                 // chunk length

typedef __attribute__((ext_vector_type(8))) short bf16x8;
typedef __attribute__((ext_vector_type(8))) unsigned short us8;
typedef __attribute__((ext_vector_type(4))) float f32x4;

__device__ __forceinline__ float sigmoidf_(float x){ return 1.f/(1.f+__expf(-x)); }
__device__ __forceinline__ float softplusf_(float x){ return fmaxf(x,0.f) + log1pf(__expf(-fabsf(x))); }
__device__ __forceinline__ unsigned short f2bf(float f){
  unsigned int u = __float_as_uint(f);
  unsigned int r = (u + 0x7fffu + ((u>>16)&1u)) >> 16;
  return (unsigned short)r;
}

// ---- f32 -> bf16 (RNE), 8 elems/thread ----
__global__ void k_f2bf(const float* __restrict__ in, unsigned short* __restrict__ out, int n8){
  int i = blockIdx.x*blockDim.x + threadIdx.x;
  if (i>=n8) return;
  const float4* p = (const float4*)(in + (size_t)i*8);
  float4 a = p[0], b = p[1];
  us8 r;
  r[0]=f2bf(a.x); r[1]=f2bf(a.y); r[2]=f2bf(a.z); r[3]=f2bf(a.w);
  r[4]=f2bf(b.x); r[5]=f2bf(b.y); r[6]=f2bf(b.z); r[7]=f2bf(b.w);
  *(us8*)(out + (size_t)i*8) = r;
}

// ---- pm[b,l,c,j] = z^j, z = concat([x, y-x]) in ORIGINAL l order ----
__global__ void k_pm(const float* __restrict__ x, const float* __restrict__ y,
                     float* __restrict__ pm){
  int idx = blockIdx.x*blockDim.x + threadIdx.x;   // (b*L+l)*16+c
  if (idx >= NBL*16) return;
  int c = idx & 15; int m = idx >> 4;
  float z;
  if (c < 8) z = x[(size_t)m*8 + c];
  else       z = y[(size_t)m*8 + (c-8)] - x[(size_t)m*8 + (c-8)];
  float p = 1.f;
  float* o = pm + (size_t)idx*POLY;
  #pragma unroll
  for (int j=0;j<POLY;++j){ o[j]=p; p*=z; }
}

// ---- ctrl_in (flipped seq) @ control_proj_w.T + b  ->  u (mamba order) ----
__global__ void k_ctrl(const float* __restrict__ x, const float* __restrict__ y,
                       const float* __restrict__ w, const float* __restrict__ b,
                       float* __restrict__ u){
  int idx = blockIdx.x*blockDim.x + threadIdx.x;   // (b*L+lm)*256+e
  if (idx >= NBL*DCTRL) return;
  int e = idx & 255; int m = idx >> 8;
  int bb = m >> 10; int lm = m & 1023; int lo = 1023 - lm;
  const float* xp = x + ((size_t)bb*1024+lo)*8;
  const float* yp = y + ((size_t)bb*1024+lo)*8;
  const float* wr = w + (size_t)e*16;
  float acc = b[e];
  #pragma unroll
  for (int d=0; d<8; ++d) acc += (yp[d]-xp[d])*wr[d];   // xdot part
  #pragma unroll
  for (int d=0; d<8; ++d) acc += yp[d]*wr[8+d];         // y part
  u[idx] = acc;
}

// ---- rmsnorm: one block per (b,l) row ----
__global__ void k_rms(const float* __restrict__ u, const float* __restrict__ nw,
                      float* __restrict__ r){
  int m = blockIdx.x; int e = threadIdx.x;
  float v = u[(size_t)m*256 + e];
  float ss = v*v;
  #pragma unroll
  for (int off=32; off>0; off>>=1) ss += __shfl_down(ss, off);
  __shared__ float sred[4];
  __shared__ float srstd;
  int wid = e>>6; int lane = e&63;
  if (lane==0) sred[wid]=ss;
  __syncthreads();
  if (e==0){ float t = sred[0]+sred[1]+sred[2]+sred[3]; srstd = rsqrtf(t*(1.f/256.f) + 1e-5f); }
  __syncthreads();
  r[(size_t)m*256+e] = v * srstd * nw[e];
}

// ---- generic NT gemm: C[m,n] = dot(A[m,:K],B[n,:K]) (+bias[n]) (+C) (act) ----
__global__ void gemm_nt(const float* __restrict__ A, int lda,
                        const float* __restrict__ B, int ldb,
                        const float* __restrict__ bias,
                        float* __restrict__ C, int ldc,
                        int M, int N, int K, int addC, int act){
  __shared__ float As[64][17];
  __shared__ float Bs[64][17];
  int tid = threadIdx.x;
  int tx = tid & 15, ty = tid >> 4;
  int m0 = blockIdx.y*64, n0 = blockIdx.x*64;
  float acc[4][4] = {};
  for (int k0=0; k0<K; k0+=16){
    #pragma unroll
    for (int q=0;q<4;++q){
      int idx = tid + q*256; int row = idx>>4, col = idx&15;
      int am = m0+row, ak = k0+col;
      As[row][col] = (am<M && ak<K) ? A[(size_t)am*lda+ak] : 0.f;
      int bn = n0+row;
      Bs[row][col] = (bn<N && ak<K) ? B[(size_t)bn*ldb+ak] : 0.f;
    }
    __syncthreads();
    #pragma unroll
    for (int kk=0;kk<16;++kk){
      float a[4], bv[4];
      #pragma unroll
      for (int i=0;i<4;++i) a[i]=As[ty*4+i][kk];
      #pragma unroll
      for (int j=0;j<4;++j) bv[j]=Bs[tx*4+j][kk];
      #pragma unroll
      for (int i=0;i<4;++i)
        #pragma unroll
        for (int j=0;j<4;++j) acc[i][j] += a[i]*bv[j];
    }
    __syncthreads();
  }
  #pragma unroll
  for (int i=0;i<4;++i){
    int m=m0+ty*4+i; if (m>=M) continue;
    #pragma unroll
    for (int j=0;j<4;++j){
      int n=n0+tx*4+j; if (n>=N) continue;
      float v = acc[i][j];
      if (bias) v += bias[n];
      if (act==1) v = softplusf_(v);
      if (addC) v += C[(size_t)m*ldc+n];
      C[(size_t)m*ldc+n]=v;
    }
  }
}

// ---- causal conv (K=4) + bias + silu on xc half of xz ----
__global__ void k_convsilu(const float* __restrict__ xz, const float* __restrict__ cw,
                           const float* __restrict__ cb, float* __restrict__ xc){
  int idx = blockIdx.x*blockDim.x + threadIdx.x;  // m*256+d
  if (idx >= NBL*256) return;
  int d = idx & 255; int m = idx >> 8;
  int bb = m>>10, l = m&1023;
  const float* w = cw + d*4;
  float acc = cb[d];
  #pragma unroll
  for (int k=0;k<4;++k){
    int ls = l - 3 + k;
    if (ls >= 0) acc += xz[((size_t)(bb*1024+ls))*512 + d] * w[k];
  }
  xc[idx] = acc * sigmoidf_(acc);
}

// ---- chunked scan pass 1 ----
__global__ void k_scan1(const float* __restrict__ delta, const float* __restrict__ dbc,
                        const float* __restrict__ xc, const float* __restrict__ alog,
                        float* __restrict__ hend, float* __restrict__ Pc){
  int blk = blockIdx.x;              // (bb*NCH + ch)*16 + dg
  int dg = blk & 15; int ch = (blk>>4) & 15; int bb = blk>>8;
  int tid = threadIdx.x; int dl = tid>>4; int s = tid&15; int d = dg*16+dl;
  float A = -__expf(alog[(size_t)d*16+s]);
  float h = 0.f, p = 1.f;
  size_t base = (size_t)bb*1024 + ch*LCH;
  #pragma unroll 4
  for (int t=0;t<LCH;++t){
    size_t mb = base + t;
    float de  = delta[mb*256+d];
    float Bv  = dbc[mb*48+16+s];
    float xcv = xc[mb*256+d];
    float a = __expf(de*A);
    h = a*h + de*Bv*xcv;
    p *= a;
  }
  size_t o = (((size_t)bb*NCH+ch)*256+d)*16+s;
  hend[o]=h; Pc[o]=p;
}

// ---- pass 2: chunk-level recurrence ----
__global__ void k_scan2(const float* __restrict__ hend, const float* __restrict__ Pc,
                        float* __restrict__ Hinit){
  int idx = blockIdx.x*blockDim.x + threadIdx.x;  // bb*4096 + d*16+s
  if (idx >= B_SZ*256*16) return;
  int bb = idx >> 12; int ds = idx & 4095;
  float H = 0.f;
  #pragma unroll
  for (int ch=0; ch<NCH; ++ch){
    size_t o = ((size_t)bb*NCH+ch)*4096 + ds;
    Hinit[o] = H;
    H = Pc[o]*H + hend[o];
  }
}

// ---- pass 3: re-run chunks from correct init, emit gated y ----
__global__ void k_scan3(const float* __restrict__ delta, const float* __restrict__ dbc,
                        const float* __restrict__ xc, const float* __restrict__ xz,
                        const float* __restrict__ alog, const float* __restrict__ dskip,
                        const float* __restrict__ Hinit, float* __restrict__ yv){
  int blk = blockIdx.x;
  int dg = blk & 15; int ch = (blk>>4) & 15; int bb = blk>>8;
  int tid = threadIdx.x; int dl = tid>>4; int s = tid&15; int d = dg*16+dl;
  float A = -__expf(alog[(size_t)d*16+s]);
  float dsk = dskip[d];
  float h = Hinit[(((size_t)bb*NCH+ch)*256+d)*16+s];
  size_t base = (size_t)bb*1024 + ch*LCH;
  #pragma unroll 2
  for (int t=0;t<LCH;++t){
    size_t mb = base + t;
    float de  = delta[mb*256+d];
    float Bv  = dbc[mb*48+16+s];
    float Cv  = dbc[mb*48+32+s];
    float xcv = xc[mb*256+d];
    float a = __expf(de*A);
    h = a*h + de*Bv*xcv;
    float yval = h*Cv;
    yval += __shfl_xor(yval,1);
    yval += __shfl_xor(yval,2);
    yval += __shfl_xor(yval,4);
    yval += __shfl_xor(yval,8);
    if (s==0){
      float zg = xz[mb*512+256+d];
      yv[mb*256+d] = (yval + dsk*xcv) * zg * sigmoidf_(zg);
    }
  }
}

// ---- flip u back to original order: state_pred out + ws copy for b_net ----
__global__ void k_storesp(const float* __restrict__ u, float* __restrict__ sp,
                          float* __restrict__ outsp){
  int idx = blockIdx.x*blockDim.x+threadIdx.x;   // m_orig*256+e
  if (idx>=NBL*256) return;
  int e = idx & 255; int m = idx >> 8;
  int bb=m>>10, l=m&1023;
  float v = u[((size_t)(bb*1024 + (1023-l)))*256 + e];
  sp[idx]=v; outsp[idx]=v;
}

// ---- fused b_net MFMA GEMM + bilinear pm contraction -> partials ----
// Tile: BM=256 (bl), BN=64 (rows), BK=32, K=256. 4 waves in 2x2 (wr: m-half, wc: n-half).
// Each wave: 128x32 output = 8x2 fragments of 16x16 via mfma_f32_16x16x32_bf16.
__global__ void __launch_bounds__(256)
k_bnet_mfma(const unsigned short* __restrict__ spb, const unsigned short* __restrict__ Wb,
            const float* __restrict__ bnb, const float* __restrict__ pm,
            float* __restrict__ part){
  __shared__ __align__(16) unsigned short Asm[256*40];  // 20KB, padded stride 40
  __shared__ __align__(16) unsigned short Bsm[64*40];   // 5KB
  __shared__ float red[2][256];

  int tid = threadIdx.x;
  int lane = tid & 63;
  int w = tid >> 6; int wr = w >> 1, wc = w & 1;
  int l15 = lane & 15, l4 = lane >> 4;
  int bx = blockIdx.x;                 // 0..399
  int m0 = blockIdx.y*256;
  int n0 = bx*64;

  f32x4 acc[8][2];
  #pragma unroll
  for (int i=0;i<8;++i)
    #pragma unroll
    for (int j=0;j<2;++j){ acc[i][j][0]=0.f; acc[i][j][1]=0.f; acc[i][j][2]=0.f; acc[i][j][3]=0.f; }

  for (int ks=0; ks<8; ++ks){
    int k0 = ks*32;
    // stage A tile: 256 rows x 32 bf16 = 1024 granules of 16B; 4 per thread
    #pragma unroll
    for (int g2=0; g2<4; ++g2){
      int g = tid + g2*256;
      int row = g>>2, c8 = g&3;
      *(us8*)&Asm[row*40 + c8*8] = *(const us8*)(spb + ((size_t)(m0+row))*256 + k0 + c8*8);
    }
    // stage B tile: 64x32 = 256 granules; 1 per thread
    {
      int row = tid>>2, c8 = tid&3;
      *(us8*)&Bsm[row*40 + c8*8] = *(const us8*)(Wb + ((size_t)(n0+row))*256 + k0 + c8*8);
    }
    __syncthreads();
    bf16x8 av[8], bv[2];
    #pragma unroll
    for (int i=0;i<8;++i) av[i] = *(bf16x8*)&Asm[(wr*128+i*16+l15)*40 + l4*8];
    #pragma unroll
    for (int j=0;j<2;++j) bv[j] = *(bf16x8*)&Bsm[(wc*32+j*16+l15)*40 + l4*8];
    #pragma unroll
    for (int i=0;i<8;++i)
      #pragma unroll
      for (int j=0;j<2;++j)
        acc[i][j] = __builtin_amdgcn_mfma_f32_16x16x32_bf16(av[i], bv[j], acc[i][j], 0,0,0);
    __syncthreads();
  }

  // epilogue: bilinear pm contraction + reduce over the 64 n's of this tile
  int c = bx/25, slot = bx%25;
  int rem0 = slot*64;
  float bnbv[2]; int kkv[2], jjv[2];
  #pragma unroll
  for (int j=0;j<2;++j){
    int nl = wc*32 + j*16 + l15;
    int rem = rem0 + nl;
    bnbv[j] = bnb[n0 + nl];
    kkv[j] = rem/40; jjv[j] = rem%40;
  }
  #pragma unroll
  for (int i=0;i<8;++i){
    #pragma unroll
    for (int q=0;q<4;++q){
      int mloc = wr*128 + i*16 + l4*4 + q;
      int m = m0 + mloc;
      const float* pk = pm + ((size_t)m*16 + c)*40;
      const float* pj = pm + ((size_t)m*16 + (15-c))*40;
      float s = 0.f;
      #pragma unroll
      for (int j=0;j<2;++j)
        s += (acc[i][j][q] + bnbv[j]) * pk[kkv[j]] * pj[jjv[j]];
      s += __shfl_xor(s,1); s += __shfl_xor(s,2);
      s += __shfl_xor(s,4); s += __shfl_xor(s,8);
      if (l15==0) red[wc][mloc] = s;
    }
  }
  __syncthreads();
  float v = red[0][tid] + red[1][tid];
  part[((size_t)slot*NBL + m0 + tid)*16 + c] = v;
}

// ---- final zdot: sum 25 partials, drop l=0 ----
__global__ void k_final(const float* __restrict__ part, float* __restrict__ out){
  int idx=blockIdx.x*blockDim.x+threadIdx.x;   // (b*1023+(l-1))*16+c
  if (idx >= B_SZ*1023*16) return;
  int c = idx & 15; int t = idx >> 4; int bb = t / 1023; int l = t % 1023 + 1;
  size_t m = (size_t)bb*1024 + l;
  float s = 0.f;
  #pragma unroll
  for (int q=0;q<NSLOT;++q) s += part[((size_t)q*NBL + m)*16 + c];
  out[idx] = s;
}

extern "C" void kernel_launch(void* const* d_in, const int* in_sizes, int n_in,
                              void* d_out, int out_size, void* d_ws, size_t ws_size,
                              hipStream_t stream) {
  const float* x    = (const float*)d_in[0];
  const float* y    = (const float*)d_in[1];
  const float* cpw  = (const float*)d_in[2];
  const float* cpb  = (const float*)d_in[3];
  const float* nw   = (const float*)d_in[4];
  const float* ipw  = (const float*)d_in[5];
  const float* cvw  = (const float*)d_in[6];
  const float* cvb  = (const float*)d_in[7];
  const float* xpw  = (const float*)d_in[8];
  const float* dtw  = (const float*)d_in[9];
  const float* dtb  = (const float*)d_in[10];
  const float* alog = (const float*)d_in[11];
  const float* dsk  = (const float*)d_in[12];
  const float* opw  = (const float*)d_in[13];
  const float* bnw  = (const float*)d_in[14];
  const float* bnb  = (const float*)d_in[15];

  float* out      = (float*)d_out;
  float* out_zdot = out;                 // 2*1023*16 = 32736
  float* out_sp   = out + 32736;         // 2*1024*256 = 524288

  float* ws = (float*)d_ws;
  size_t off = 0;
  float* u     = ws + off; off += (size_t)NBL*256;      // [0, 524288)
  float* r     = ws + off; off += (size_t)NBL*256;
  float* xz    = ws + off; off += (size_t)NBL*512;
  float* xc    = ws + off; off += (size_t)NBL*256;
  float* dbc   = ws + off; off += (size_t)NBL*48;
  float* delta = ws + off; off += (size_t)NBL*256;
  float* yv    = ws + off; off += (size_t)NBL*256;      // ends at 3,768,320
  float* sp    = ws + off; off += (size_t)NBL*256;
  float* pm    = ws + off; off += (size_t)NBL*16*POLY;
  float* part  = ws + off; off += (size_t)NSLOT*NBL*16;
  float* hend  = ws + off; off += (size_t)B_SZ*NCH*256*16;
  float* Pc    = ws + off; off += (size_t)B_SZ*NCH*256*16;
  float* Hinit = ws + off; off += (size_t)B_SZ*NCH*256*16;
  unsigned short* spb = (unsigned short*)(ws + off); off += (size_t)NBL*256/2;
  // Wb (25600*256 bf16 = 3,276,800 floats) overlays u..yv (3,768,320 floats),
  // all dead after k_storesp. Converted AFTER the mamba loop.
  unsigned short* Wb  = (unsigned short*)ws;

  k_pm  <<<(NBL*16+255)/256, 256, 0, stream>>>(x, y, pm);
  k_ctrl<<<(NBL*256+255)/256, 256, 0, stream>>>(x, y, cpw, cpb, u);

  for (int i=0;i<NL;++i){
    k_rms<<<NBL, 256, 0, stream>>>(u, nw + i*256, r);
    gemm_nt<<<dim3(512/64, NBL/64), 256, 0, stream>>>(r, 256, ipw + (size_t)i*512*256, 256,
                                                      nullptr, xz, 512, NBL, 512, 256, 0, 0);
    k_convsilu<<<(NBL*256+255)/256, 256, 0, stream>>>(xz, cvw + i*256*4, cvb + i*256, xc);
    gemm_nt<<<dim3(1, NBL/64), 256, 0, stream>>>(xc, 256, xpw + (size_t)i*48*256, 256,
                                                 nullptr, dbc, 48, NBL, 48, 256, 0, 0);
    gemm_nt<<<dim3(4, NBL/64), 256, 0, stream>>>(dbc, 48, dtw + (size_t)i*256*16, 16,
                                                 dtb + i*256, delta, 256, NBL, 256, 16, 0, 1);
    k_scan1<<<B_SZ*NCH*16, 256, 0, stream>>>(delta, dbc, xc, alog + (size_t)i*256*16, hend, Pc);
    k_scan2<<<(B_SZ*256*16+255)/256, 256, 0, stream>>>(hend, Pc, Hinit);
    k_scan3<<<B_SZ*NCH*16, 256, 0, stream>>>(delta, dbc, xc, xz, alog + (size_t)i*256*16,
                                             dsk + i*256, Hinit, yv);
    gemm_nt<<<dim3(4, NBL/64), 256, 0, stream>>>(yv, 256, opw + (size_t)i*256*256, 256,
                                                 nullptr, u, 256, NBL, 256, 256, 1, 0);
  }

  k_storesp<<<(NBL*256+255)/256, 256, 0, stream>>>(u, sp, out_sp);
  k_f2bf<<<(NBL*256/8 + 255)/256, 256, 0, stream>>>(sp, spb, NBL*256/8);
  // now u..yv are dead -> safe to overwrite with Wb
  k_f2bf<<<(NROWS*256/8 + 255)/256, 256, 0, stream>>>(bnw, Wb, NROWS*256/8);
  k_bnet_mfma<<<dim3(NROWS/64, NBL/256), 256, 0, stream>>>(spb, Wb, bnb, pm, part);
  k_final<<<(B_SZ*1023*16+255)/256, 256, 0, stream>>>(part, out_zdot);
}

// Round 5
// 491.272 us; speedup vs baseline: 5.7731x; 1.1230x over previous
//
#include <hip/hip_runtime.h>
#include <hip/hip_bf16.h>

#define B_SZ   2
#define LSEQ   1024
#define DD     8
#define DCTRL  256
#define POLY   40
#define NL     2
#define DSTATE 16
#define DCONV  4
#define DINNER 256
#define DTRANK 16
#define NBL    (B_SZ*LSEQ)        // 2048
#define NROWS  (2*DD*POLY*POLY)   // 25600
#define NSLOT  25                 // 1600/64 r-tiles per channel
#define NCH    16                 // scan chunks
#define LCH    64                 // chunk length

typedef __attribute__((ext_vector_type(8))) short bf16x8;
typedef __attribute__((ext_vector_type(8))) unsigned short us8;
typedef __attribute__((ext_vector_type(4))) float f32x4;

__device__ __forceinline__ float sigmoidf_(float x){ return 1.f/(1.f+__expf(-x)); }
__device__ __forceinline__ float softplusf_(float x){ return fmaxf(x,0.f) + log1pf(__expf(-fabsf(x))); }
__device__ __forceinline__ unsigned short f2bf(float f){
  unsigned int u = __float_as_uint(f);
  unsigned int r = (u + 0x7fffu + ((u>>16)&1u)) >> 16;
  return (unsigned short)r;
}

// ---- f32 -> bf16 (RNE), 8 elems/thread ----
__global__ void k_f2bf(const float* __restrict__ in, unsigned short* __restrict__ out, int n8){
  int i = blockIdx.x*blockDim.x + threadIdx.x;
  if (i>=n8) return;
  const float4* p = (const float4*)(in + (size_t)i*8);
  float4 a = p[0], b = p[1];
  us8 r;
  r[0]=f2bf(a.x); r[1]=f2bf(a.y); r[2]=f2bf(a.z); r[3]=f2bf(a.w);
  r[4]=f2bf(b.x); r[5]=f2bf(b.y); r[6]=f2bf(b.z); r[7]=f2bf(b.w);
  *(us8*)(out + (size_t)i*8) = r;
}

// ---- pmt[c][j][m] = z(m,c)^j (TRANSPOSED layout for coalesced epilogue) ----
__global__ void k_pm(const float* __restrict__ x, const float* __restrict__ y,
                     float* __restrict__ pmt){
  int idx = blockIdx.x*blockDim.x + threadIdx.x;   // c*2048 + m
  if (idx >= 16*NBL) return;
  int m = idx & (NBL-1); int c = idx >> 11;
  float z;
  if (c < 8) z = x[(size_t)m*8 + c];
  else       z = y[(size_t)m*8 + (c-8)] - x[(size_t)m*8 + (c-8)];
  float p = 1.f;
  #pragma unroll
  for (int j=0;j<POLY;++j){ pmt[((size_t)c*POLY+j)*NBL + m] = p; p*=z; }
}

// ---- ctrl_in (flipped seq) @ control_proj_w.T + b  ->  u (mamba order) ----
__global__ void k_ctrl(const float* __restrict__ x, const float* __restrict__ y,
                       const float* __restrict__ w, const float* __restrict__ b,
                       float* __restrict__ u){
  int idx = blockIdx.x*blockDim.x + threadIdx.x;   // (b*L+lm)*256+e
  if (idx >= NBL*DCTRL) return;
  int e = idx & 255; int m = idx >> 8;
  int bb = m >> 10; int lm = m & 1023; int lo = 1023 - lm;
  const float* xp = x + ((size_t)bb*1024+lo)*8;
  const float* yp = y + ((size_t)bb*1024+lo)*8;
  const float* wr = w + (size_t)e*16;
  float acc = b[e];
  #pragma unroll
  for (int d=0; d<8; ++d) acc += (yp[d]-xp[d])*wr[d];   // xdot part
  #pragma unroll
  for (int d=0; d<8; ++d) acc += yp[d]*wr[8+d];         // y part
  u[idx] = acc;
}

// ---- rmsnorm: one block per (b,l) row ----
__global__ void k_rms(const float* __restrict__ u, const float* __restrict__ nw,
                      float* __restrict__ r){
  int m = blockIdx.x; int e = threadIdx.x;
  float v = u[(size_t)m*256 + e];
  float ss = v*v;
  #pragma unroll
  for (int off=32; off>0; off>>=1) ss += __shfl_down(ss, off);
  __shared__ float sred[4];
  __shared__ float srstd;
  int wid = e>>6; int lane = e&63;
  if (lane==0) sred[wid]=ss;
  __syncthreads();
  if (e==0){ float t = sred[0]+sred[1]+sred[2]+sred[3]; srstd = rsqrtf(t*(1.f/256.f) + 1e-5f); }
  __syncthreads();
  r[(size_t)m*256+e] = v * srstd * nw[e];
}

// ---- generic NT gemm: C[m,n] = dot(A[m,:K],B[n,:K]) (+bias[n]) (+C) (act) ----
__global__ void gemm_nt(const float* __restrict__ A, int lda,
                        const float* __restrict__ B, int ldb,
                        const float* __restrict__ bias,
                        float* __restrict__ C, int ldc,
                        int M, int N, int K, int addC, int act){
  __shared__ float As[64][17];
  __shared__ float Bs[64][17];
  int tid = threadIdx.x;
  int tx = tid & 15, ty = tid >> 4;
  int m0 = blockIdx.y*64, n0 = blockIdx.x*64;
  float acc[4][4] = {};
  for (int k0=0; k0<K; k0+=16){
    #pragma unroll
    for (int q=0;q<4;++q){
      int idx = tid + q*256; int row = idx>>4, col = idx&15;
      int am = m0+row, ak = k0+col;
      As[row][col] = (am<M && ak<K) ? A[(size_t)am*lda+ak] : 0.f;
      int bn = n0+row;
      Bs[row][col] = (bn<N && ak<K) ? B[(size_t)bn*ldb+ak] : 0.f;
    }
    __syncthreads();
    #pragma unroll
    for (int kk=0;kk<16;++kk){
      float a[4], bv[4];
      #pragma unroll
      for (int i=0;i<4;++i) a[i]=As[ty*4+i][kk];
      #pragma unroll
      for (int j=0;j<4;++j) bv[j]=Bs[tx*4+j][kk];
      #pragma unroll
      for (int i=0;i<4;++i)
        #pragma unroll
        for (int j=0;j<4;++j) acc[i][j] += a[i]*bv[j];
    }
    __syncthreads();
  }
  #pragma unroll
  for (int i=0;i<4;++i){
    int m=m0+ty*4+i; if (m>=M) continue;
    #pragma unroll
    for (int j=0;j<4;++j){
      int n=n0+tx*4+j; if (n>=N) continue;
      float v = acc[i][j];
      if (bias) v += bias[n];
      if (act==1) v = softplusf_(v);
      if (addC) v += C[(size_t)m*ldc+n];
      C[(size_t)m*ldc+n]=v;
    }
  }
}

// ---- causal conv (K=4) + bias + silu on xc half of xz ----
__global__ void k_convsilu(const float* __restrict__ xz, const float* __restrict__ cw,
                           const float* __restrict__ cb, float* __restrict__ xc){
  int idx = blockIdx.x*blockDim.x + threadIdx.x;  // m*256+d
  if (idx >= NBL*256) return;
  int d = idx & 255; int m = idx >> 8;
  int bb = m>>10, l = m&1023;
  const float* w = cw + d*4;
  float acc = cb[d];
  #pragma unroll
  for (int k=0;k<4;++k){
    int ls = l - 3 + k;
    if (ls >= 0) acc += xz[((size_t)(bb*1024+ls))*512 + d] * w[k];
  }
  xc[idx] = acc * sigmoidf_(acc);
}

// ---- chunked scan pass 1 ----
__global__ void k_scan1(const float* __restrict__ delta, const float* __restrict__ dbc,
                        const float* __restrict__ xc, const float* __restrict__ alog,
                        float* __restrict__ hend, float* __restrict__ Pc){
  int blk = blockIdx.x;              // (bb*NCH + ch)*16 + dg
  int dg = blk & 15; int ch = (blk>>4) & 15; int bb = blk>>8;
  int tid = threadIdx.x; int dl = tid>>4; int s = tid&15; int d = dg*16+dl;
  float A = -__expf(alog[(size_t)d*16+s]);
  float h = 0.f, p = 1.f;
  size_t base = (size_t)bb*1024 + ch*LCH;
  #pragma unroll 4
  for (int t=0;t<LCH;++t){
    size_t mb = base + t;
    float de  = delta[mb*256+d];
    float Bv  = dbc[mb*48+16+s];
    float xcv = xc[mb*256+d];
    float a = __expf(de*A);
    h = a*h + de*Bv*xcv;
    p *= a;
  }
  size_t o = (((size_t)bb*NCH+ch)*256+d)*16+s;
  hend[o]=h; Pc[o]=p;
}

// ---- pass 2: chunk-level recurrence ----
__global__ void k_scan2(const float* __restrict__ hend, const float* __restrict__ Pc,
                        float* __restrict__ Hinit){
  int idx = blockIdx.x*blockDim.x + threadIdx.x;  // bb*4096 + d*16+s
  if (idx >= B_SZ*256*16) return;
  int bb = idx >> 12; int ds = idx & 4095;
  float H = 0.f;
  #pragma unroll
  for (int ch=0; ch<NCH; ++ch){
    size_t o = ((size_t)bb*NCH+ch)*4096 + ds;
    Hinit[o] = H;
    H = Pc[o]*H + hend[o];
  }
}

// ---- pass 3: re-run chunks from correct init, emit gated y ----
__global__ void k_scan3(const float* __restrict__ delta, const float* __restrict__ dbc,
                        const float* __restrict__ xc, const float* __restrict__ xz,
                        const float* __restrict__ alog, const float* __restrict__ dskip,
                        const float* __restrict__ Hinit, float* __restrict__ yv){
  int blk = blockIdx.x;
  int dg = blk & 15; int ch = (blk>>4) & 15; int bb = blk>>8;
  int tid = threadIdx.x; int dl = tid>>4; int s = tid&15; int d = dg*16+dl;
  float A = -__expf(alog[(size_t)d*16+s]);
  float dsk = dskip[d];
  float h = Hinit[(((size_t)bb*NCH+ch)*256+d)*16+s];
  size_t base = (size_t)bb*1024 + ch*LCH;
  #pragma unroll 2
  for (int t=0;t<LCH;++t){
    size_t mb = base + t;
    float de  = delta[mb*256+d];
    float Bv  = dbc[mb*48+16+s];
    float Cv  = dbc[mb*48+32+s];
    float xcv = xc[mb*256+d];
    float a = __expf(de*A);
    h = a*h + de*Bv*xcv;
    float yval = h*Cv;
    yval += __shfl_xor(yval,1);
    yval += __shfl_xor(yval,2);
    yval += __shfl_xor(yval,4);
    yval += __shfl_xor(yval,8);
    if (s==0){
      float zg = xz[mb*512+256+d];
      yv[mb*256+d] = (yval + dsk*xcv) * zg * sigmoidf_(zg);
    }
  }
}

// ---- flip u back to original order: state_pred out + f32 copy + bf16 copy ----
__global__ void k_storesp(const float* __restrict__ u, float* __restrict__ outsp,
                          unsigned short* __restrict__ spb){
  int idx = blockIdx.x*blockDim.x+threadIdx.x;   // m_orig*256+e
  if (idx>=NBL*256) return;
  int e = idx & 255; int m = idx >> 8;
  int bb=m>>10, l=m&1023;
  float v = u[((size_t)(bb*1024 + (1023-l)))*256 + e];
  outsp[idx]=v; spb[idx]=f2bf(v);
}

// ---- fused b_net MFMA GEMM + bilinear pm contraction -> partials ----
// Tile: BM=256 (bl), BN=64 (rows), BK=32, K=256. 8 waves in 4x2 (wr, wc).
// Each wave: 64x32 output = 4x2 fragments of 16x16 via mfma_f32_16x16x32_bf16.
__global__ void __launch_bounds__(512)
k_bnet_mfma(const unsigned short* __restrict__ spb, const unsigned short* __restrict__ Wb,
            const float* __restrict__ bnb, const float* __restrict__ pmt,
            float* __restrict__ part){
  __shared__ __align__(16) unsigned short Asm[256*40];  // 20KB, padded stride 40
  __shared__ __align__(16) unsigned short Bsm[64*40];   // 5KB
  __shared__ float red[2][256];

  int tid = threadIdx.x;
  int lane = tid & 63;
  int w = tid >> 6;                 // 0..7
  int wr = w >> 1, wc = w & 1;      // wr 0..3, wc 0..1
  int l15 = lane & 15, l4 = lane >> 4;
  int bx = blockIdx.x;              // 0..399
  int m0 = blockIdx.y*256;
  int n0 = bx*64;

  f32x4 acc[4][2];
  #pragma unroll
  for (int i=0;i<4;++i)
    #pragma unroll
    for (int j=0;j<2;++j){ acc[i][j][0]=0.f; acc[i][j][1]=0.f; acc[i][j][2]=0.f; acc[i][j][3]=0.f; }

  for (int ks=0; ks<8; ++ks){
    int k0 = ks*32;
    // stage A tile: 256 rows x 32 bf16 = 1024 granules of 16B; 2 per thread
    #pragma unroll
    for (int g2=0; g2<2; ++g2){
      int g = tid + g2*512;
      int row = g>>2, c8 = g&3;
      *(us8*)&Asm[row*40 + c8*8] = *(const us8*)(spb + ((size_t)(m0+row))*256 + k0 + c8*8);
    }
    // stage B tile: 64x32 = 256 granules
    if (tid < 256){
      int row = tid>>2, c8 = tid&3;
      *(us8*)&Bsm[row*40 + c8*8] = *(const us8*)(Wb + ((size_t)(n0+row))*256 + k0 + c8*8);
    }
    __syncthreads();
    bf16x8 av[4], bv[2];
    #pragma unroll
    for (int i=0;i<4;++i) av[i] = *(bf16x8*)&Asm[(wr*64+i*16+l15)*40 + l4*8];
    #pragma unroll
    for (int j=0;j<2;++j) bv[j] = *(bf16x8*)&Bsm[(wc*32+j*16+l15)*40 + l4*8];
    #pragma unroll
    for (int i=0;i<4;++i)
      #pragma unroll
      for (int j=0;j<2;++j)
        acc[i][j] = __builtin_amdgcn_mfma_f32_16x16x32_bf16(av[i], bv[j], acc[i][j], 0,0,0);
    __syncthreads();
  }

  // epilogue: bilinear pmt contraction + reduce over the 64 n's of this tile
  int c = bx/25, slot = bx%25;
  int rem0 = slot*64;
  float bnbv[2]; int kkv[2], jjv[2];
  #pragma unroll
  for (int j=0;j<2;++j){
    int nl = wc*32 + j*16 + l15;
    int rem = rem0 + nl;
    bnbv[j] = bnb[n0 + nl];
    kkv[j] = rem/40; jjv[j] = rem%40;
  }
  const float* pc  = pmt + (size_t)c*POLY*NBL;
  const float* pcf = pmt + (size_t)(15-c)*POLY*NBL;
  #pragma unroll
  for (int i=0;i<4;++i){
    int mb = m0 + wr*64 + i*16 + l4*4;     // q=0..3 contiguous, 16B aligned
    f32x4 s; s[0]=0.f; s[1]=0.f; s[2]=0.f; s[3]=0.f;
    #pragma unroll
    for (int j=0;j<2;++j){
      f32x4 pk = *(const f32x4*)&pc [(size_t)kkv[j]*NBL + mb];
      f32x4 pj = *(const f32x4*)&pcf[(size_t)jjv[j]*NBL + mb];
      #pragma unroll
      for (int q=0;q<4;++q) s[q] += (acc[i][j][q] + bnbv[j]) * pk[q] * pj[q];
    }
    #pragma unroll
    for (int q=0;q<4;++q){
      float t = s[q];
      t += __shfl_xor(t,1); t += __shfl_xor(t,2);
      t += __shfl_xor(t,4); t += __shfl_xor(t,8);
      if (l15==0) red[wc][wr*64 + i*16 + l4*4 + q] = t;
    }
  }
  __syncthreads();
  if (tid < 256){
    float v = red[0][tid] + red[1][tid];
    part[((size_t)slot*NBL + m0 + tid)*16 + c] = v;
  }
}

// ---- final zdot: sum 25 partials, drop l=0 ----
__global__ void k_final(const float* __restrict__ part, float* __restrict__ out){
  int idx=blockIdx.x*blockDim.x+threadIdx.x;   // (b*1023+(l-1))*16+c
  if (idx >= B_SZ*1023*16) return;
  int c = idx & 15; int t = idx >> 4; int bb = t / 1023; int l = t % 1023 + 1;
  size_t m = (size_t)bb*1024 + l;
  float s = 0.f;
  #pragma unroll
  for (int q=0;q<NSLOT;++q) s += part[((size_t)q*NBL + m)*16 + c];
  out[idx] = s;
}

extern "C" void kernel_launch(void* const* d_in, const int* in_sizes, int n_in,
                              void* d_out, int out_size, void* d_ws, size_t ws_size,
                              hipStream_t stream) {
  const float* x    = (const float*)d_in[0];
  const float* y    = (const float*)d_in[1];
  const float* cpw  = (const float*)d_in[2];
  const float* cpb  = (const float*)d_in[3];
  const float* nw   = (const float*)d_in[4];
  const float* ipw  = (const float*)d_in[5];
  const float* cvw  = (const float*)d_in[6];
  const float* cvb  = (const float*)d_in[7];
  const float* xpw  = (const float*)d_in[8];
  const float* dtw  = (const float*)d_in[9];
  const float* dtb  = (const float*)d_in[10];
  const float* alog = (const float*)d_in[11];
  const float* dsk  = (const float*)d_in[12];
  const float* opw  = (const float*)d_in[13];
  const float* bnw  = (const float*)d_in[14];
  const float* bnb  = (const float*)d_in[15];

  float* out      = (float*)d_out;
  float* out_zdot = out;                 // 2*1023*16 = 32736
  float* out_sp   = out + 32736;         // 2*1024*256 = 524288

  float* ws = (float*)d_ws;
  size_t off = 0;
  float* u     = ws + off; off += (size_t)NBL*256;      // [0, 524288)
  float* r     = ws + off; off += (size_t)NBL*256;
  float* xz    = ws + off; off += (size_t)NBL*512;
  float* xc    = ws + off; off += (size_t)NBL*256;
  float* dbc   = ws + off; off += (size_t)NBL*48;
  float* delta = ws + off; off += (size_t)NBL*256;
  float* yv    = ws + off; off += (size_t)NBL*256;      // ends at 3,768,320
  float* pmt   = ws + off; off += (size_t)NBL*16*POLY;
  float* part  = ws + off; off += (size_t)NSLOT*NBL*16;
  float* hend  = ws + off; off += (size_t)B_SZ*NCH*256*16;
  float* Pc    = ws + off; off += (size_t)B_SZ*NCH*256*16;
  float* Hinit = ws + off; off += (size_t)B_SZ*NCH*256*16;
  unsigned short* spb = (unsigned short*)(ws + off); off += (size_t)NBL*256/2;
  // Wb (25600*256 bf16 = 3,276,800 floats) overlays u..yv (3,768,320 floats),
  // all dead after k_storesp. Converted AFTER the mamba loop.
  unsigned short* Wb  = (unsigned short*)ws;

  k_pm  <<<(16*NBL+255)/256, 256, 0, stream>>>(x, y, pmt);
  k_ctrl<<<(NBL*256+255)/256, 256, 0, stream>>>(x, y, cpw, cpb, u);

  for (int i=0;i<NL;++i){
    k_rms<<<NBL, 256, 0, stream>>>(u, nw + i*256, r);
    gemm_nt<<<dim3(512/64, NBL/64), 256, 0, stream>>>(r, 256, ipw + (size_t)i*512*256, 256,
                                                      nullptr, xz, 512, NBL, 512, 256, 0, 0);
    k_convsilu<<<(NBL*256+255)/256, 256, 0, stream>>>(xz, cvw + i*256*4, cvb + i*256, xc);
    gemm_nt<<<dim3(1, NBL/64), 256, 0, stream>>>(xc, 256, xpw + (size_t)i*48*256, 256,
                                                 nullptr, dbc, 48, NBL, 48, 256, 0, 0);
    gemm_nt<<<dim3(4, NBL/64), 256, 0, stream>>>(dbc, 48, dtw + (size_t)i*256*16, 16,
                                                 dtb + i*256, delta, 256, NBL, 256, 16, 0, 1);
    k_scan1<<<B_SZ*NCH*16, 256, 0, stream>>>(delta, dbc, xc, alog + (size_t)i*256*16, hend, Pc);
    k_scan2<<<(B_SZ*256*16+255)/256, 256, 0, stream>>>(hend, Pc, Hinit);
    k_scan3<<<B_SZ*NCH*16, 256, 0, stream>>>(delta, dbc, xc, xz, alog + (size_t)i*256*16,
                                             dsk + i*256, Hinit, yv);
    gemm_nt<<<dim3(4, NBL/64), 256, 0, stream>>>(yv, 256, opw + (size_t)i*256*256, 256,
                                                 nullptr, u, 256, NBL, 256, 256, 1, 0);
  }

  k_storesp<<<(NBL*256+255)/256, 256, 0, stream>>>(u, out_sp, spb);
  // now u..yv are dead -> safe to overwrite with Wb
  k_f2bf<<<(NROWS*256/8 + 255)/256, 256, 0, stream>>>(bnw, Wb, NROWS*256/8);
  k_bnet_mfma<<<dim3(NROWS/64, NBL/256), 512, 0, stream>>>(spb, Wb, bnb, pmt, part);
  k_final<<<(B_SZ*1023*16+255)/256, 256, 0, stream>>>(part, out_zdot);
}

// Round 7
// 282.774 us; speedup vs baseline: 10.0297x; 1.7373x over previous
//
#include <hip/hip_runtime.h>
#include <hip/hip_bf16.h>

#define B_SZ   2
#define LSEQ   1024
#define DD     8
#define DCTRL  256
#define POLY   40
#define NL     2
#define DSTATE 16
#define DCONV  4
#define DINNER 256
#define DTRANK 16
#define NBL    (B_SZ*LSEQ)        // 2048
#define NROWS  (2*DD*POLY*POLY)   // 25600
#define NSLOT  25                 // 1600/64 r-tiles per channel
#define NCH    32                 // scan chunks
#define LCH    32                 // chunk length

typedef __attribute__((ext_vector_type(8))) short bf16x8;
typedef __attribute__((ext_vector_type(8))) unsigned short us8;
typedef __attribute__((ext_vector_type(4))) float f32x4;

__device__ __forceinline__ float sigmoidf_(float x){ return 1.f/(1.f+__expf(-x)); }
__device__ __forceinline__ float softplusf_(float x){ return fmaxf(x,0.f) + log1pf(__expf(-fabsf(x))); }
__device__ __forceinline__ unsigned short f2bf(float f){
  unsigned int u = __float_as_uint(f);
  unsigned int r = (u + 0x7fffu + ((u>>16)&1u)) >> 16;
  return (unsigned short)r;
}

// ---- f32 -> bf16 (RNE), 8 elems/thread ----
__global__ void k_f2bf(const float* __restrict__ in, unsigned short* __restrict__ out, int n8){
  int i = blockIdx.x*blockDim.x + threadIdx.x;
  if (i>=n8) return;
  const float4* p = (const float4*)(in + (size_t)i*8);
  float4 a = p[0], b = p[1];
  us8 r;
  r[0]=f2bf(a.x); r[1]=f2bf(a.y); r[2]=f2bf(a.z); r[3]=f2bf(a.w);
  r[4]=f2bf(b.x); r[5]=f2bf(b.y); r[6]=f2bf(b.z); r[7]=f2bf(b.w);
  *(us8*)(out + (size_t)i*8) = r;
}

// ---- Wcomb[l][288][256]: rows 0..255 = dtw@xpw[:16] (W_eff); rows 256..287 = xpw[16:48] ----
__global__ void k_wcomb(const float* __restrict__ dtw, const float* __restrict__ xpw,
                        unsigned short* __restrict__ wcomb){
  int idx = blockIdx.x*blockDim.x + threadIdx.x;
  if (idx >= NL*288*256) return;
  int e = idx & 255; int row = (idx>>8) % 288; int l = idx / (288*256);
  float v;
  if (row < 256){
    float s=0.f;
    #pragma unroll
    for (int r=0;r<16;++r) s += dtw[((size_t)l*256+row)*16+r] * xpw[((size_t)l*48+r)*256+e];
    v = s;
  } else {
    v = xpw[((size_t)l*48 + (row-240))*256 + e];
  }
  wcomb[idx] = f2bf(v);
}

// ---- pmt[c][j][m] = z(m,c)^j (transposed for coalesced epilogue) ----
__global__ void k_pm(const float* __restrict__ x, const float* __restrict__ y,
                     float* __restrict__ pmt){
  int idx = blockIdx.x*blockDim.x + threadIdx.x;   // c*2048 + m
  if (idx >= 16*NBL) return;
  int m = idx & (NBL-1); int c = idx >> 11;
  float z;
  if (c < 8) z = x[(size_t)m*8 + c];
  else       z = y[(size_t)m*8 + (c-8)] - x[(size_t)m*8 + (c-8)];
  float p = 1.f;
  #pragma unroll
  for (int j=0;j<POLY;++j){ pmt[((size_t)c*POLY+j)*NBL + m] = p; p*=z; }
}

// ---- ctrl_in (flipped seq) @ control_proj_w.T + b  ->  u (mamba order) ----
__global__ void k_ctrl(const float* __restrict__ x, const float* __restrict__ y,
                       const float* __restrict__ w, const float* __restrict__ b,
                       float* __restrict__ u){
  int idx = blockIdx.x*blockDim.x + threadIdx.x;   // (b*L+lm)*256+e
  if (idx >= NBL*DCTRL) return;
  int e = idx & 255; int m = idx >> 8;
  int bb = m >> 10; int lm = m & 1023; int lo = 1023 - lm;
  const float* xp = x + ((size_t)bb*1024+lo)*8;
  const float* yp = y + ((size_t)bb*1024+lo)*8;
  const float* wr = w + (size_t)e*16;
  float acc = b[e];
  #pragma unroll
  for (int d=0; d<8; ++d) acc += (yp[d]-xp[d])*wr[d];
  #pragma unroll
  for (int d=0; d<8; ++d) acc += yp[d]*wr[8+d];
  u[idx] = acc;
}

// ---- rmsnorm -> bf16 ----
__global__ void k_rms(const float* __restrict__ u, const float* __restrict__ nw,
                      unsigned short* __restrict__ rb){
  int m = blockIdx.x; int e = threadIdx.x;
  float v = u[(size_t)m*256 + e];
  float ss = v*v;
  #pragma unroll
  for (int off=32; off>0; off>>=1) ss += __shfl_down(ss, off);
  __shared__ float sred[4];
  __shared__ float srstd;
  int wid = e>>6; int lane = e&63;
  if (lane==0) sred[wid]=ss;
  __syncthreads();
  if (e==0){ float t = sred[0]+sred[1]+sred[2]+sred[3]; srstd = rsqrtf(t*(1.f/256.f) + 1e-5f); }
  __syncthreads();
  rb[(size_t)m*256+e] = f2bf(v * srstd * nw[e]);
}

// ---- generic MFMA NT GEMM: A[2048xK] bf16, B[NxK] bf16 ----
// tile 128x64, 4 waves (2x2), per-wave 64x32 (4x2 frags of 16x16x32).
// mode 0: C0[m*ldc+n] = acc
// mode 1: C0[m*ldc+n] += acc
// mode 2: n<256 -> C0[m*256+n] = softplus(acc+bias[n]); 256<=n<N -> C1[m*32+n-256] = acc
__global__ void __launch_bounds__(256)
gemm_bf(const unsigned short* __restrict__ A, const unsigned short* __restrict__ B,
        int N, int K, const float* __restrict__ bias,
        float* __restrict__ C0, float* __restrict__ C1, int ldc, int mode){
  __shared__ __align__(16) unsigned short Asm[128*40];
  __shared__ __align__(16) unsigned short Bsm[64*40];
  int tid = threadIdx.x;
  int lane = tid & 63;
  int w = tid >> 6; int wr = w >> 1, wc = w & 1;
  int l15 = lane & 15, l4 = lane >> 4;
  int m0 = blockIdx.y*128, n0 = blockIdx.x*64;

  f32x4 acc[4][2];
  #pragma unroll
  for (int i=0;i<4;++i)
    #pragma unroll
    for (int j=0;j<2;++j){ acc[i][j][0]=0.f; acc[i][j][1]=0.f; acc[i][j][2]=0.f; acc[i][j][3]=0.f; }

  int nks = K >> 5;
  for (int ks=0; ks<nks; ++ks){
    int k0 = ks*32;
    #pragma unroll
    for (int g2=0; g2<2; ++g2){
      int g = tid + g2*256; int row = g>>2, c8 = g&3;
      *(us8*)&Asm[row*40 + c8*8] = *(const us8*)(A + (size_t)(m0+row)*K + k0 + c8*8);
    }
    {
      int row = tid>>2, c8 = tid&3; int bn = n0+row;
      us8 v;
      if (bn < N){
        v = *(const us8*)(B + (size_t)bn*K + k0 + c8*8);
      } else {
        for (int z=0;z<8;++z) v[z]=0;
      }
      *(us8*)&Bsm[row*40 + c8*8] = v;
    }
    __syncthreads();
    bf16x8 av[4], bv[2];
    #pragma unroll
    for (int i=0;i<4;++i) av[i] = *(bf16x8*)&Asm[(wr*64+i*16+l15)*40 + l4*8];
    #pragma unroll
    for (int j=0;j<2;++j) bv[j] = *(bf16x8*)&Bsm[(wc*32+j*16+l15)*40 + l4*8];
    #pragma unroll
    for (int i=0;i<4;++i)
      #pragma unroll
      for (int j=0;j<2;++j)
        acc[i][j] = __builtin_amdgcn_mfma_f32_16x16x32_bf16(av[i], bv[j], acc[i][j], 0,0,0);
    __syncthreads();
  }

  #pragma unroll
  for (int i=0;i<4;++i){
    #pragma unroll
    for (int j=0;j<2;++j){
      int n = n0 + wc*32 + j*16 + l15;
      #pragma unroll
      for (int q=0;q<4;++q){
        int m = m0 + wr*64 + i*16 + l4*4 + q;
        float v = acc[i][j][q];
        if (mode==0){
          C0[(size_t)m*ldc + n] = v;
        } else if (mode==1){
          C0[(size_t)m*ldc + n] += v;
        } else {
          if (n < 256) C0[(size_t)m*256 + n] = softplusf_(v + bias[n]);
          else if (n < N) C1[(size_t)m*32 + (n-256)] = v;
        }
      }
    }
  }
}

// ---- causal conv (K=4) + bias + silu; outputs f32 + bf16 ----
__global__ void k_convsilu(const float* __restrict__ xz, const float* __restrict__ cw,
                           const float* __restrict__ cb, float* __restrict__ xc,
                           unsigned short* __restrict__ xcb){
  int idx = blockIdx.x*blockDim.x + threadIdx.x;  // m*256+d
  if (idx >= NBL*256) return;
  int d = idx & 255; int m = idx >> 8;
  int bb = m>>10, l = m&1023;
  const float* w = cw + d*4;
  float acc = cb[d];
  #pragma unroll
  for (int k=0;k<4;++k){
    int ls = l - 3 + k;
    if (ls >= 0) acc += xz[((size_t)(bb*1024+ls))*512 + d] * w[k];
  }
  float v = acc * sigmoidf_(acc);
  xc[idx] = v; xcb[idx] = f2bf(v);
}

// ---- chunked scan pass 1: per-chunk end-state + cumprod ----
__global__ void k_scan1(const float* __restrict__ delta, const float* __restrict__ bc,
                        const float* __restrict__ xc, const float* __restrict__ alog,
                        float* __restrict__ hend, float* __restrict__ Pc){
  int blk = blockIdx.x;              // bb*512 + ch*16 + dg
  int dg = blk & 15; int ch = (blk>>4) & (NCH-1); int bb = blk >> 9;
  int tid = threadIdx.x; int dl = tid>>4; int s = tid&15; int d = dg*16+dl;
  float A = -__expf(alog[(size_t)d*16+s]);
  float h = 0.f, p = 1.f;
  size_t base = (size_t)bb*1024 + ch*LCH;
  #pragma unroll 4
  for (int t=0;t<LCH;++t){
    size_t mb = base + t;
    float de  = delta[mb*256+d];
    float Bv  = bc[mb*32+s];
    float xcv = xc[mb*256+d];
    float a = __expf(de*A);
    h = a*h + de*Bv*xcv;
    p *= a;
  }
  size_t o = (((size_t)bb*NCH+ch)*256+d)*16+s;
  hend[o]=h; Pc[o]=p;
}

// ---- pass 2: chunk-level recurrence ----
__global__ void k_scan2(const float* __restrict__ hend, const float* __restrict__ Pc,
                        float* __restrict__ Hinit){
  int idx = blockIdx.x*blockDim.x + threadIdx.x;  // bb*4096 + d*16+s
  if (idx >= B_SZ*256*16) return;
  int bb = idx >> 12; int ds = idx & 4095;
  float H = 0.f;
  #pragma unroll
  for (int ch=0; ch<NCH; ++ch){
    size_t o = ((size_t)bb*NCH+ch)*4096 + ds;
    Hinit[o] = H;
    H = Pc[o]*H + hend[o];
  }
}

// ---- pass 3: re-run chunks from correct init, emit gated y (bf16) ----
__global__ void k_scan3(const float* __restrict__ delta, const float* __restrict__ bc,
                        const float* __restrict__ xc, const float* __restrict__ xz,
                        const float* __restrict__ alog, const float* __restrict__ dskip,
                        const float* __restrict__ Hinit, unsigned short* __restrict__ yvb){
  int blk = blockIdx.x;
  int dg = blk & 15; int ch = (blk>>4) & (NCH-1); int bb = blk >> 9;
  int tid = threadIdx.x; int dl = tid>>4; int s = tid&15; int d = dg*16+dl;
  float A = -__expf(alog[(size_t)d*16+s]);
  float dsk = dskip[d];
  float h = Hinit[(((size_t)bb*NCH+ch)*256+d)*16+s];
  size_t base = (size_t)bb*1024 + ch*LCH;
  #pragma unroll 2
  for (int t=0;t<LCH;++t){
    size_t mb = base + t;
    float de  = delta[mb*256+d];
    float Bv  = bc[mb*32+s];
    float Cv  = bc[mb*32+16+s];
    float xcv = xc[mb*256+d];
    float a = __expf(de*A);
    h = a*h + de*Bv*xcv;
    float yval = h*Cv;
    yval += __shfl_xor(yval,1);
    yval += __shfl_xor(yval,2);
    yval += __shfl_xor(yval,4);
    yval += __shfl_xor(yval,8);
    if (s==0){
      float zg = xz[mb*512+256+d];
      yvb[mb*256+d] = f2bf((yval + dsk*xcv) * zg * sigmoidf_(zg));
    }
  }
}

// ---- flip u back to original order: state_pred out + bf16 copy ----
__global__ void k_storesp(const float* __restrict__ u, float* __restrict__ outsp,
                          unsigned short* __restrict__ spb){
  int idx = blockIdx.x*blockDim.x+threadIdx.x;   // m_orig*256+e
  if (idx>=NBL*256) return;
  int e = idx & 255; int m = idx >> 8;
  int bb=m>>10, l=m&1023;
  float v = u[((size_t)(bb*1024 + (1023-l)))*256 + e];
  outsp[idx]=v; spb[idx]=f2bf(v);
}

// ---- fused b_net MFMA GEMM + bilinear pm contraction -> partials ----
__global__ void __launch_bounds__(512)
k_bnet_mfma(const unsigned short* __restrict__ spb, const unsigned short* __restrict__ Wb,
            const float* __restrict__ bnb, const float* __restrict__ pmt,
            float* __restrict__ part){
  __shared__ __align__(16) unsigned short Asm[256*40];
  __shared__ __align__(16) unsigned short Bsm[64*40];
  __shared__ float red[2][256];

  int tid = threadIdx.x;
  int lane = tid & 63;
  int w = tid >> 6;
  int wr = w >> 1, wc = w & 1;
  int l15 = lane & 15, l4 = lane >> 4;
  int bx = blockIdx.x;
  int m0 = blockIdx.y*256;
  int n0 = bx*64;

  f32x4 acc[4][2];
  #pragma unroll
  for (int i=0;i<4;++i)
    #pragma unroll
    for (int j=0;j<2;++j){ acc[i][j][0]=0.f; acc[i][j][1]=0.f; acc[i][j][2]=0.f; acc[i][j][3]=0.f; }

  for (int ks=0; ks<8; ++ks){
    int k0 = ks*32;
    #pragma unroll
    for (int g2=0; g2<2; ++g2){
      int g = tid + g2*512;
      int row = g>>2, c8 = g&3;
      *(us8*)&Asm[row*40 + c8*8] = *(const us8*)(spb + ((size_t)(m0+row))*256 + k0 + c8*8);
    }
    if (tid < 256){
      int row = tid>>2, c8 = tid&3;
      *(us8*)&Bsm[row*40 + c8*8] = *(const us8*)(Wb + ((size_t)(n0+row))*256 + k0 + c8*8);
    }
    __syncthreads();
    bf16x8 av[4], bv[2];
    #pragma unroll
    for (int i=0;i<4;++i) av[i] = *(bf16x8*)&Asm[(wr*64+i*16+l15)*40 + l4*8];
    #pragma unroll
    for (int j=0;j<2;++j) bv[j] = *(bf16x8*)&Bsm[(wc*32+j*16+l15)*40 + l4*8];
    #pragma unroll
    for (int i=0;i<4;++i)
      #pragma unroll
      for (int j=0;j<2;++j)
        acc[i][j] = __builtin_amdgcn_mfma_f32_16x16x32_bf16(av[i], bv[j], acc[i][j], 0,0,0);
    __syncthreads();
  }

  int c = bx/25, slot = bx%25;
  int rem0 = slot*64;
  float bnbv[2]; int kkv[2], jjv[2];
  #pragma unroll
  for (int j=0;j<2;++j){
    int nl = wc*32 + j*16 + l15;
    int rem = rem0 + nl;
    bnbv[j] = bnb[n0 + nl];
    kkv[j] = rem/40; jjv[j] = rem%40;
  }
  const float* pc  = pmt + (size_t)c*POLY*NBL;
  const float* pcf = pmt + (size_t)(15-c)*POLY*NBL;
  #pragma unroll
  for (int i=0;i<4;++i){
    int mb = m0 + wr*64 + i*16 + l4*4;
    f32x4 s; s[0]=0.f; s[1]=0.f; s[2]=0.f; s[3]=0.f;
    #pragma unroll
    for (int j=0;j<2;++j){
      f32x4 pk = *(const f32x4*)&pc [(size_t)kkv[j]*NBL + mb];
      f32x4 pj = *(const f32x4*)&pcf[(size_t)jjv[j]*NBL + mb];
      #pragma unroll
      for (int q=0;q<4;++q) s[q] += (acc[i][j][q] + bnbv[j]) * pk[q] * pj[q];
    }
    #pragma unroll
    for (int q=0;q<4;++q){
      float t = s[q];
      t += __shfl_xor(t,1); t += __shfl_xor(t,2);
      t += __shfl_xor(t,4); t += __shfl_xor(t,8);
      if (l15==0) red[wc][wr*64 + i*16 + l4*4 + q] = t;
    }
  }
  __syncthreads();
  if (tid < 256){
    float v = red[0][tid] + red[1][tid];
    part[((size_t)slot*NBL + m0 + tid)*16 + c] = v;
  }
}

// ---- final zdot: sum 25 partials, drop l=0 ----
__global__ void k_final(const float* __restrict__ part, float* __restrict__ out){
  int idx=blockIdx.x*blockDim.x+threadIdx.x;
  if (idx >= B_SZ*1023*16) return;
  int c = idx & 15; int t = idx >> 4; int bb = t / 1023; int l = t % 1023 + 1;
  size_t m = (size_t)bb*1024 + l;
  float s = 0.f;
  #pragma unroll
  for (int q=0;q<NSLOT;++q) s += part[((size_t)q*NBL + m)*16 + c];
  out[idx] = s;
}

extern "C" void kernel_launch(void* const* d_in, const int* in_sizes, int n_in,
                              void* d_out, int out_size, void* d_ws, size_t ws_size,
                              hipStream_t stream) {
  const float* x    = (const float*)d_in[0];
  const float* y    = (const float*)d_in[1];
  const float* cpw  = (const float*)d_in[2];
  const float* cpb  = (const float*)d_in[3];
  const float* nw   = (const float*)d_in[4];
  const float* ipw  = (const float*)d_in[5];
  const float* cvw  = (const float*)d_in[6];
  const float* cvb  = (const float*)d_in[7];
  const float* xpw  = (const float*)d_in[8];
  const float* dtw  = (const float*)d_in[9];
  const float* dtb  = (const float*)d_in[10];
  const float* alog = (const float*)d_in[11];
  const float* dsk  = (const float*)d_in[12];
  const float* opw  = (const float*)d_in[13];
  const float* bnw  = (const float*)d_in[14];
  const float* bnb  = (const float*)d_in[15];

  float* out      = (float*)d_out;
  float* out_zdot = out;                 // 2*1023*16
  float* out_sp   = out + 32736;         // 2*1024*256

  float* ws = (float*)d_ws;
  size_t off = 0;
  // --- region overlaid by Wb after k_storesp (all dead by then) ---
  float* u     = ws + off; off += (size_t)NBL*256;       //  524288
  unsigned short* rb = (unsigned short*)(ws + off); off += (size_t)NBL*256/2;  // 262144
  float* xz    = ws + off; off += (size_t)NBL*512;       // 1048576
  float* xc    = ws + off; off += (size_t)NBL*256;       //  524288
  unsigned short* xcb = (unsigned short*)(ws + off); off += (size_t)NBL*256/2; // 262144
  float* delta = ws + off; off += (size_t)NBL*256;       //  524288
  float* bcm   = ws + off; off += (size_t)NBL*32;        //   65536
  unsigned short* yvb = (unsigned short*)(ws + off); off += (size_t)NBL*256/2; // 262144
  // running total = 3,473,408 floats >= Wb's 3,276,800 -> safe overlay
  // --- persistent region ---
  float* pmt   = ws + off; off += (size_t)NBL*16*POLY;
  float* part  = ws + off; off += (size_t)NSLOT*NBL*16;
  float* hend  = ws + off; off += (size_t)B_SZ*NCH*256*16;
  float* Pc    = ws + off; off += (size_t)B_SZ*NCH*256*16;
  float* Hinit = ws + off; off += (size_t)B_SZ*NCH*256*16;
  unsigned short* spb  = (unsigned short*)(ws + off); off += (size_t)NBL*256/2;
  unsigned short* ipwb = (unsigned short*)(ws + off); off += (size_t)NL*512*256/2;
  unsigned short* opwb = (unsigned short*)(ws + off); off += (size_t)NL*256*256/2;
  unsigned short* wcomb= (unsigned short*)(ws + off); off += (size_t)NL*288*256/2;
  unsigned short* Wb   = (unsigned short*)ws;   // overlay of u..yvb

  // weight prep (bf16)
  k_f2bf <<<(NL*512*256/8+255)/256, 256, 0, stream>>>(ipw, ipwb, NL*512*256/8);
  k_f2bf <<<(NL*256*256/8+255)/256, 256, 0, stream>>>(opw, opwb, NL*256*256/8);
  k_wcomb<<<(NL*288*256+255)/256, 256, 0, stream>>>(dtw, xpw, wcomb);

  k_pm  <<<(16*NBL+255)/256, 256, 0, stream>>>(x, y, pmt);
  k_ctrl<<<(NBL*256+255)/256, 256, 0, stream>>>(x, y, cpw, cpb, u);

  for (int i=0;i<NL;++i){
    k_rms<<<NBL, 256, 0, stream>>>(u, nw + i*256, rb);
    gemm_bf<<<dim3(8,16), 256, 0, stream>>>(rb, ipwb + (size_t)i*512*256, 512, 256,
                                            nullptr, xz, nullptr, 512, 0);
    k_convsilu<<<(NBL*256+255)/256, 256, 0, stream>>>(xz, cvw + i*256*4, cvb + i*256, xc, xcb);
    gemm_bf<<<dim3(5,16), 256, 0, stream>>>(xcb, wcomb + (size_t)i*288*256, 288, 256,
                                            dtb + i*256, delta, bcm, 256, 2);
    k_scan1<<<B_SZ*NCH*16, 256, 0, stream>>>(delta, bcm, xc, alog + (size_t)i*256*16, hend, Pc);
    k_scan2<<<(B_SZ*256*16+255)/256, 256, 0, stream>>>(hend, Pc, Hinit);
    k_scan3<<<B_SZ*NCH*16, 256, 0, stream>>>(delta, bcm, xc, xz, alog + (size_t)i*256*16,
                                             dsk + i*256, Hinit, yvb);
    gemm_bf<<<dim3(4,16), 256, 0, stream>>>(yvb, opwb + (size_t)i*256*256, 256, 256,
                                            nullptr, u, nullptr, 256, 1);
  }

  k_storesp<<<(NBL*256+255)/256, 256, 0, stream>>>(u, out_sp, spb);
  // u..yvb now dead -> overlay with Wb
  k_f2bf<<<(NROWS*256/8 + 255)/256, 256, 0, stream>>>(bnw, Wb, NROWS*256/8);
  k_bnet_mfma<<<dim3(NROWS/64, NBL/256), 512, 0, stream>>>(spb, Wb, bnb, pmt, part);
  k_final<<<(B_SZ*1023*16+255)/256, 256, 0, stream>>>(part, out_zdot);
}